// Round 5
// baseline (709.190 us; speedup 1.0000x reference)
//
#include <hip/hip_runtime.h>
#include <hip/hip_bf16.h>
#include <math.h>

#define N_NODES 100000
#define N_EDGES 1600000
#define D 128
#define NB 391          // buckets = ceil(N/256), bucket = dst >> 8
#define BSTRIDE 6000    // staging cap/bucket (avg 4092, sigma 64 -> 14 sigma headroom)

// ---- workspace layout (bytes), total 109,600,000 ----
#define OFF_SSRC 0                    // int[E]      sorted src ids   (6,400,000)
#define OFF_OFFS 6400000              // int[N+1]    CSR offsets (400,004)
#define OFF_PACK 6800016              // W_pack bf16 hi/lo fragments (393,216)
#define OFF_GC   7193232              // gcur[NB]
#define OFF_BB   7195296              // bbase[NB]
#define OFF_AH   7200000              // ushort[N*D] plane A hi (25,600,000)
#define OFF_AL   32800000             // ushort[N*D] plane A lo
#define OFF_BH   58400000             // ushort[N*D] plane B hi  (sort staging aliases here)
#define OFF_BL   84000000             // ushort[N*D] plane B lo  -> ends 109,600,000

typedef __attribute__((ext_vector_type(8))) short short8;
typedef __attribute__((ext_vector_type(4))) float floatx4;

__device__ __forceinline__ unsigned short f2bf(float f) {
    unsigned int u = __float_as_uint(f);
    u += 0x7fffu + ((u >> 16) & 1u);   // RNE
    return (unsigned short)(u >> 16);
}
__device__ __forceinline__ float bf2f(unsigned short h) {
    return __uint_as_float(((unsigned int)h) << 16);
}

// ---------------- pass 1: partition edges into 391 coarse buckets ----------------
__global__ __launch_bounds__(256) void part_kernel(const int* __restrict__ src,
                                                   const int* __restrict__ dst,
                                                   int* __restrict__ gcur,
                                                   uint2* __restrict__ staging) {
    __shared__ int hist[NB];
    __shared__ int base[NB];
    int t = threadIdx.x;
    int e0 = blockIdx.x * 4096;
    for (int i = t; i < NB; i += 256) hist[i] = 0;
    __syncthreads();
    int d[16];
#pragma unroll
    for (int i = 0; i < 16; ++i) {
        int e = e0 + i * 256 + t;
        d[i] = (e < N_EDGES) ? dst[e] : -1;
        if (d[i] >= 0) atomicAdd(&hist[d[i] >> 8], 1);
    }
    __syncthreads();
    for (int i = t; i < NB; i += 256) {
        int h = hist[i];
        base[i] = h ? atomicAdd(&gcur[i], h) : 0;
    }
    __syncthreads();
    for (int i = t; i < NB; i += 256) hist[i] = 0;   // reuse as local cursor
    __syncthreads();
#pragma unroll
    for (int i = 0; i < 16; ++i) {
        if (d[i] >= 0) {
            int e = e0 + i * 256 + t;
            int b = d[i] >> 8;
            int slot = atomicAdd(&hist[b], 1);
            staging[b * BSTRIDE + base[b] + slot] =
                make_uint2((unsigned)src[e], (unsigned)(d[i] & 255));
        }
    }
}

// ---------------- exclusive scan of bucket totals ----------------
__global__ void bscan_kernel(const int* __restrict__ gcur, int* __restrict__ bbase,
                             int* __restrict__ offs) {
    __shared__ int sh[512];
    int t = threadIdx.x;
    int v = (t < NB) ? gcur[t] : 0;
    sh[t] = v;
    __syncthreads();
    for (int off = 1; off < 512; off <<= 1) {
        int y = (t >= off) ? sh[t - off] : 0;
        __syncthreads();
        sh[t] += y;
        __syncthreads();
    }
    if (t < NB) bbase[t] = sh[t] - v;
    if (t == 0) offs[N_NODES] = N_EDGES;
}

// ---------------- pass 2: sort each bucket in LDS, emit CSR ----------------
__global__ __launch_bounds__(256) void bsort_kernel(const uint2* __restrict__ staging,
                                                    const int* __restrict__ gcur,
                                                    const int* __restrict__ bbase,
                                                    int* __restrict__ offs,
                                                    int* __restrict__ s_src) {
    __shared__ int cnt[256];
    __shared__ int scn[256];
    __shared__ int ssrc[BSTRIDE];
    int b = blockIdx.x;
    int t = threadIdx.x;
    int n = gcur[b];
    int base_out = bbase[b];
    cnt[t] = 0;
    __syncthreads();
    for (int e = t; e < n; e += 256) {
        uint2 v = staging[b * BSTRIDE + e];
        atomicAdd(&cnt[v.y], 1);
    }
    __syncthreads();
    int v = cnt[t];
    scn[t] = v;
    __syncthreads();
    for (int off = 1; off < 256; off <<= 1) {
        int y = (t >= off) ? scn[t - off] : 0;
        __syncthreads();
        scn[t] += y;
        __syncthreads();
    }
    int ex = scn[t] - v;                 // exclusive prefix
    int node = b * 256 + t;
    if (node < N_NODES) offs[node] = base_out + ex;
    cnt[t] = ex;                         // reuse as cursor
    __syncthreads();
    for (int e = t; e < n; e += 256) {
        uint2 w = staging[b * BSTRIDE + e];
        int slot = atomicAdd(&cnt[w.y], 1);
        ssrc[slot] = (int)w.x;
    }
    __syncthreads();
    for (int e = t; e < n; e += 256) s_src[base_out + e] = ssrc[e];
}

// ---------------- weight pack: fragment-ordered bf16 hi/lo ----------------
__global__ void pack_kernel(const float* __restrict__ Wl0, const float* __restrict__ Wr0,
                            const float* __restrict__ Wl1, const float* __restrict__ Wr1,
                            const float* __restrict__ Wl2, const float* __restrict__ Wr2,
                            unsigned short* __restrict__ pack) {
    int tid = blockIdx.x * blockDim.x + threadIdx.x;   // 3*32768 threads
    int l = tid >> 15;
    int r = tid & 32767;
    int k = r >> 7;
    int n = r & 127;
    const float* Wl = (l == 0) ? Wl0 : (l == 1) ? Wl1 : Wl2;
    const float* Wr = (l == 0) ? Wr0 : (l == 1) ? Wr1 : Wr2;
    float v = (k < 128) ? Wl[k * 128 + n] : Wr[(k - 128) * 128 + n];
    unsigned short hi = f2bf(v);
    unsigned short lo = f2bf(v - bf2f(hi));
    int ct = n >> 4, ks = k >> 5, lane = ((k >> 3) & 3) * 16 + (n & 15), j = k & 7;
    int idx = ((ct * 8 + ks) * 64 + lane) * 8 + j;
    pack[l * 65536 + idx] = hi;
    pack[l * 65536 + 32768 + idx] = lo;
}

// ---------------- fp32 x -> bf16 hi/lo planes ----------------
__global__ __launch_bounds__(256) void cvt_kernel(const float* __restrict__ x,
                                                  unsigned int* __restrict__ Xhi,
                                                  unsigned int* __restrict__ Xlo) {
    int i = blockIdx.x * 256 + threadIdx.x;      // N*64 uints, 2 channels each
    float2 v = ((const float2*)x)[i];
    unsigned short h0 = f2bf(v.x), h1 = f2bf(v.y);
    unsigned short l0 = f2bf(v.x - bf2f(h0)), l1 = f2bf(v.y - bf2f(h1));
    Xhi[i] = (unsigned int)h0 | ((unsigned int)h1 << 16);
    Xlo[i] = (unsigned int)l0 | ((unsigned int)l1 << 16);
}

// ---------------- fused: gather-mean + MFMA linear + LN(+ELU | +L2norm) ----------------
// Per wave: 16 output rows. Phase 1 gathers neighbor means into a private LDS
// region (no barriers anywhere); phase 2 runs the split-bf16 MFMA K-loop with
// A(mean) from LDS and A(h) from global planes; epilogue LN -> ping-pong planes.
__global__ __launch_bounds__(256) void fused_kernel(const unsigned short* __restrict__ Xh,
                                                    const unsigned short* __restrict__ Xl,
                                                    const int* __restrict__ s_src,
                                                    const int* __restrict__ offs,
                                                    const unsigned short* __restrict__ packh,
                                                    const unsigned short* __restrict__ packl,
                                                    const float* __restrict__ bl,
                                                    const float* __restrict__ g,
                                                    const float* __restrict__ b,
                                                    unsigned short* __restrict__ Yh,
                                                    unsigned short* __restrict__ Yl,
                                                    float* __restrict__ outf, int last) {
    __shared__ float mlds[4][16][132];   // per-wave region; 132 stride -> 2-way banks (free)
    int t = threadIdx.x;
    int lane = t & 63;
    int wid = t >> 6;
    int tilebase = blockIdx.x * 64 + wid * 16;
    const unsigned int* Xh32 = (const unsigned int*)Xh;

    // ---- phase 1: gather means for this wave's 16 rows ----
    for (int r = 0; r < 16; ++r) {
        int node = tilebase + r;
        if (node >= N_NODES) break;                 // wave-uniform
        int beg = offs[node], end = offs[node + 1];
        float a0 = 0.f, a1 = 0.f, b0 = 0.f, b1 = 0.f;
        int e = beg;
        for (; e + 3 < end; e += 4) {
            int s0 = s_src[e], s1 = s_src[e + 1], s2 = s_src[e + 2], s3 = s_src[e + 3];
            unsigned int u0 = Xh32[s0 * 64 + lane];
            unsigned int u1 = Xh32[s1 * 64 + lane];
            unsigned int u2 = Xh32[s2 * 64 + lane];
            unsigned int u3 = Xh32[s3 * 64 + lane];
            a0 += bf2f((unsigned short)u0) + bf2f((unsigned short)u1);
            a1 += bf2f((unsigned short)(u0 >> 16)) + bf2f((unsigned short)(u1 >> 16));
            b0 += bf2f((unsigned short)u2) + bf2f((unsigned short)u3);
            b1 += bf2f((unsigned short)(u2 >> 16)) + bf2f((unsigned short)(u3 >> 16));
        }
        for (; e < end; ++e) {
            unsigned int u = Xh32[s_src[e] * 64 + lane];
            a0 += bf2f((unsigned short)u);
            a1 += bf2f((unsigned short)(u >> 16));
        }
        float inv = 1.0f / fmaxf((float)(end - beg), 1.0f);
        mlds[wid][r][lane * 2] = (a0 + b0) * inv;
        mlds[wid][r][lane * 2 + 1] = (a1 + b1) * inv;
    }
    // no __syncthreads: each wave reads only its own LDS region (lgkmcnt handles it)

    int colb = lane & 15;
    int quad = lane >> 4;
    int kq = quad * 8;
    int rowA = min(tilebase + colb, N_NODES - 1);

    floatx4 acc[8];
#pragma unroll
    for (int ct = 0; ct < 8; ++ct) acc[ct] = (floatx4){0.f, 0.f, 0.f, 0.f};

    // ---- ks 0..3: mean @ Wl (A from LDS, split hi/lo in-register) ----
#pragma unroll
    for (int ks = 0; ks < 4; ++ks) {
        const float* p = &mlds[wid][colb][ks * 32 + kq];
        float4 v0 = *(const float4*)p;
        float4 v1 = *(const float4*)(p + 4);
        float v[8] = {v0.x, v0.y, v0.z, v0.w, v1.x, v1.y, v1.z, v1.w};
        short8 ah, al;
#pragma unroll
        for (int j = 0; j < 8; ++j) {
            unsigned short hi = f2bf(v[j]);
            ah[j] = (short)hi;
            al[j] = (short)f2bf(v[j] - bf2f(hi));
        }
#pragma unroll
        for (int ct = 0; ct < 8; ++ct) {
            int fo = ((ct * 8 + ks) << 9) + (lane << 3);
            short8 bh = *(const short8*)(packh + fo);
            short8 bo = *(const short8*)(packl + fo);
            acc[ct] = __builtin_amdgcn_mfma_f32_16x16x32_bf16(ah, bh, acc[ct], 0, 0, 0);
            acc[ct] = __builtin_amdgcn_mfma_f32_16x16x32_bf16(al, bh, acc[ct], 0, 0, 0);
            acc[ct] = __builtin_amdgcn_mfma_f32_16x16x32_bf16(ah, bo, acc[ct], 0, 0, 0);
        }
    }
    // ---- ks 4..7: h @ Wr (A from global hi/lo planes) ----
#pragma unroll
    for (int ks = 4; ks < 8; ++ks) {
        long o = (long)rowA * D + (ks - 4) * 32 + kq;
        short8 ah = *(const short8*)(Xh + o);
        short8 al = *(const short8*)(Xl + o);
#pragma unroll
        for (int ct = 0; ct < 8; ++ct) {
            int fo = ((ct * 8 + ks) << 9) + (lane << 3);
            short8 bh = *(const short8*)(packh + fo);
            short8 bo = *(const short8*)(packl + fo);
            acc[ct] = __builtin_amdgcn_mfma_f32_16x16x32_bf16(ah, bh, acc[ct], 0, 0, 0);
            acc[ct] = __builtin_amdgcn_mfma_f32_16x16x32_bf16(al, bh, acc[ct], 0, 0, 0);
            acc[ct] = __builtin_amdgcn_mfma_f32_16x16x32_bf16(ah, bo, acc[ct], 0, 0, 0);
        }
    }

    // ---- epilogue: bias + LN (+ELU | +L2norm) ----
    float bb[8], gg[8], b2[8];
#pragma unroll
    for (int ct = 0; ct < 8; ++ct) {
        bb[ct] = bl[ct * 16 + colb];
        gg[ct] = g[ct * 16 + colb];
        b2[ct] = b[ct * 16 + colb];
    }
#pragma unroll
    for (int ct = 0; ct < 8; ++ct)
#pragma unroll
        for (int e = 0; e < 4; ++e) acc[ct][e] += bb[ct];

    float mu[4], rstd[4];
#pragma unroll
    for (int e = 0; e < 4; ++e) {
        float s = 0.f;
#pragma unroll
        for (int ct = 0; ct < 8; ++ct) s += acc[ct][e];
        s += __shfl_xor(s, 1); s += __shfl_xor(s, 2);
        s += __shfl_xor(s, 4); s += __shfl_xor(s, 8);
        mu[e] = s * (1.0f / 128.0f);
    }
#pragma unroll
    for (int e = 0; e < 4; ++e) {
        float q = 0.f;
#pragma unroll
        for (int ct = 0; ct < 8; ++ct) {
            float d = acc[ct][e] - mu[e];
            q += d * d;
        }
        q += __shfl_xor(q, 1); q += __shfl_xor(q, 2);
        q += __shfl_xor(q, 4); q += __shfl_xor(q, 8);
        rstd[e] = rsqrtf(q * (1.0f / 128.0f) + 1e-5f);
    }
#pragma unroll
    for (int ct = 0; ct < 8; ++ct)
#pragma unroll
        for (int e = 0; e < 4; ++e) {
            float y = (acc[ct][e] - mu[e]) * rstd[e] * gg[ct] + b2[ct];
            if (!last) y = (y > 0.f) ? y : expm1f(y);
            acc[ct][e] = y;
        }
    if (last) {
#pragma unroll
        for (int e = 0; e < 4; ++e) {
            float ss = 0.f;
#pragma unroll
            for (int ct = 0; ct < 8; ++ct) {
                float y = acc[ct][e];
                ss += y * y;
            }
            ss += __shfl_xor(ss, 1); ss += __shfl_xor(ss, 2);
            ss += __shfl_xor(ss, 4); ss += __shfl_xor(ss, 8);
            float inv = 1.0f / fmaxf(sqrtf(ss), 1e-12f);
#pragma unroll
            for (int ct = 0; ct < 8; ++ct) acc[ct][e] *= inv;
        }
#pragma unroll
        for (int e = 0; e < 4; ++e) {
            int row = tilebase + quad * 4 + e;
            if (row < N_NODES) {
#pragma unroll
                for (int ct = 0; ct < 8; ++ct)
                    outf[(long)row * D + ct * 16 + colb] = acc[ct][e];
            }
        }
    } else {
#pragma unroll
        for (int e = 0; e < 4; ++e) {
            int row = tilebase + quad * 4 + e;
            if (row < N_NODES) {
#pragma unroll
                for (int ct = 0; ct < 8; ++ct) {
                    float y = acc[ct][e];
                    unsigned short hh = f2bf(y);
                    unsigned short ll = f2bf(y - bf2f(hh));
                    long o = (long)row * D + ct * 16 + colb;
                    Yh[o] = hh;
                    Yl[o] = ll;
                }
            }
        }
    }
}

extern "C" void kernel_launch(void* const* d_in, const int* in_sizes, int n_in,
                              void* d_out, int out_size, void* d_ws, size_t ws_size,
                              hipStream_t stream) {
    const float* x = (const float*)d_in[0];
    const int* edges = (const int*)d_in[1];
    const int* src = edges;
    const int* dst = edges + N_EDGES;
    const float* Wl[3] = {(const float*)d_in[2], (const float*)d_in[7],  (const float*)d_in[12]};
    const float* bl[3] = {(const float*)d_in[3], (const float*)d_in[8],  (const float*)d_in[13]};
    const float* Wr[3] = {(const float*)d_in[4], (const float*)d_in[9],  (const float*)d_in[14]};
    const float* g[3]  = {(const float*)d_in[5], (const float*)d_in[10], (const float*)d_in[15]};
    const float* b[3]  = {(const float*)d_in[6], (const float*)d_in[11], (const float*)d_in[16]};

    char* ws = (char*)d_ws;
    int* s_src = (int*)(ws + OFF_SSRC);
    int* offs  = (int*)(ws + OFF_OFFS);
    unsigned short* wpack = (unsigned short*)(ws + OFF_PACK);
    int* gcur  = (int*)(ws + OFF_GC);
    int* bbase = (int*)(ws + OFF_BB);
    unsigned short* AH = (unsigned short*)(ws + OFF_AH);
    unsigned short* AL = (unsigned short*)(ws + OFF_AL);
    unsigned short* BH = (unsigned short*)(ws + OFF_BH);
    unsigned short* BL = (unsigned short*)(ws + OFF_BL);
    uint2* staging = (uint2*)(ws + OFF_BH);    // aliases plane B; dead before layer-0 write
    float* out = (float*)d_out;

    // ---- locality-preserving bucket sort of edges by dst ----
    hipMemsetAsync(gcur, 0, NB * sizeof(int), stream);
    part_kernel<<<(N_EDGES + 4095) / 4096, 256, 0, stream>>>(src, dst, gcur, staging);
    bscan_kernel<<<1, 512, 0, stream>>>(gcur, bbase, offs);
    bsort_kernel<<<NB, 256, 0, stream>>>(staging, gcur, bbase, offs, s_src);
    // weights -> bf16 hi/lo fragments; x -> bf16 hi/lo planes
    pack_kernel<<<(3 * 32768) / 256, 256, 0, stream>>>(Wl[0], Wr[0], Wl[1], Wr[1], Wl[2], Wr[2], wpack);
    cvt_kernel<<<(N_NODES * 64) / 256, 256, 0, stream>>>(x, (unsigned int*)AH, (unsigned int*)AL);

    const int FB = (N_NODES + 63) / 64;  // 1563 blocks, 4 waves x 16 rows
    unsigned short* ph[3] = {wpack, wpack + 65536, wpack + 131072};

    // ---- layer 0: A -> B ----
    fused_kernel<<<FB, 256, 0, stream>>>(AH, AL, s_src, offs, ph[0], ph[0] + 32768,
                                         bl[0], g[0], b[0], BH, BL, nullptr, 0);
    // ---- layer 1: B -> A ----
    fused_kernel<<<FB, 256, 0, stream>>>(BH, BL, s_src, offs, ph[1], ph[1] + 32768,
                                         bl[1], g[1], b[1], AH, AL, nullptr, 0);
    // ---- layer 2: A -> out (fp32, + L2 normalize) ----
    fused_kernel<<<FB, 256, 0, stream>>>(AH, AL, s_src, offs, ph[2], ph[2] + 32768,
                                         bl[2], g[2], b[2], nullptr, nullptr, out, 1);
}

// Round 6
// 636.705 us; speedup vs baseline: 1.1138x; 1.1138x over previous
//
#include <hip/hip_runtime.h>
#include <hip/hip_bf16.h>
#include <math.h>

#define N_NODES 100000
#define N_EDGES 1600000
#define D 128
#define NB 391          // buckets = ceil(N/256), bucket = dst >> 8
#define BSTRIDE 6000    // staging cap/bucket (avg 4092, sigma 64 -> 14 sigma headroom)

// ---- workspace layout (bytes), total 109,604,112 ----
#define OFF_SSRC 0                    // int[E]      sorted src ids   (6,400,000)
#define OFF_OFFS 6400000              // int[N+1]    CSR offsets
#define OFF_PACK 6800016              // W_pack bf16 hi/lo fragments (393,216)
#define OFF_GC   7193232              // gcur[NB]
#define OFF_BB   7195296              // bbase[NB]
#define OFF_M    7204112              // float[N*D] mean (51.2 MB); sort staging (18.8 MB) aliases
#define OFF_XHI  58404112             // ushort[N*D]  h hi plane (25.6 MB)
#define OFF_XLO  84004112             // ushort[N*D]  h lo plane (25.6 MB)

typedef __attribute__((ext_vector_type(8))) short short8;
typedef __attribute__((ext_vector_type(4))) float floatx4;

__device__ __forceinline__ unsigned short f2bf(float f) {
    unsigned int u = __float_as_uint(f);
    u += 0x7fffu + ((u >> 16) & 1u);   // RNE
    return (unsigned short)(u >> 16);
}
__device__ __forceinline__ float bf2f(unsigned short h) {
    return __uint_as_float(((unsigned int)h) << 16);
}

// ---------------- pass 1: partition edges into 391 coarse buckets ----------------
__global__ __launch_bounds__(256) void part_kernel(const int* __restrict__ src,
                                                   const int* __restrict__ dst,
                                                   int* __restrict__ gcur,
                                                   uint2* __restrict__ staging) {
    __shared__ int hist[NB];
    __shared__ int base[NB];
    int t = threadIdx.x;
    int e0 = blockIdx.x * 4096;
    for (int i = t; i < NB; i += 256) hist[i] = 0;
    __syncthreads();
    int d[16];
#pragma unroll
    for (int i = 0; i < 16; ++i) {
        int e = e0 + i * 256 + t;
        d[i] = (e < N_EDGES) ? dst[e] : -1;
        if (d[i] >= 0) atomicAdd(&hist[d[i] >> 8], 1);
    }
    __syncthreads();
    for (int i = t; i < NB; i += 256) {
        int h = hist[i];
        base[i] = h ? atomicAdd(&gcur[i], h) : 0;
    }
    __syncthreads();
    for (int i = t; i < NB; i += 256) hist[i] = 0;   // reuse as local cursor
    __syncthreads();
#pragma unroll
    for (int i = 0; i < 16; ++i) {
        if (d[i] >= 0) {
            int e = e0 + i * 256 + t;
            int b = d[i] >> 8;
            int slot = atomicAdd(&hist[b], 1);
            staging[b * BSTRIDE + base[b] + slot] =
                make_uint2((unsigned)src[e], (unsigned)(d[i] & 255));
        }
    }
}

// ---------------- exclusive scan of bucket totals ----------------
__global__ void bscan_kernel(const int* __restrict__ gcur, int* __restrict__ bbase,
                             int* __restrict__ offs) {
    __shared__ int sh[512];
    int t = threadIdx.x;
    int v = (t < NB) ? gcur[t] : 0;
    sh[t] = v;
    __syncthreads();
    for (int off = 1; off < 512; off <<= 1) {
        int y = (t >= off) ? sh[t - off] : 0;
        __syncthreads();
        sh[t] += y;
        __syncthreads();
    }
    if (t < NB) bbase[t] = sh[t] - v;
    if (t == 0) offs[N_NODES] = N_EDGES;
}

// ---------------- pass 2: sort each bucket in LDS, emit CSR ----------------
__global__ __launch_bounds__(256) void bsort_kernel(const uint2* __restrict__ staging,
                                                    const int* __restrict__ gcur,
                                                    const int* __restrict__ bbase,
                                                    int* __restrict__ offs,
                                                    int* __restrict__ s_src) {
    __shared__ int cnt[256];
    __shared__ int scn[256];
    __shared__ int ssrc[BSTRIDE];
    int b = blockIdx.x;
    int t = threadIdx.x;
    int n = gcur[b];
    int base_out = bbase[b];
    cnt[t] = 0;
    __syncthreads();
    for (int e = t; e < n; e += 256) {
        uint2 v = staging[b * BSTRIDE + e];
        atomicAdd(&cnt[v.y], 1);
    }
    __syncthreads();
    int v = cnt[t];
    scn[t] = v;
    __syncthreads();
    for (int off = 1; off < 256; off <<= 1) {
        int y = (t >= off) ? scn[t - off] : 0;
        __syncthreads();
        scn[t] += y;
        __syncthreads();
    }
    int ex = scn[t] - v;                 // exclusive prefix
    int node = b * 256 + t;
    if (node < N_NODES) offs[node] = base_out + ex;
    cnt[t] = ex;                         // reuse as cursor
    __syncthreads();
    for (int e = t; e < n; e += 256) {
        uint2 w = staging[b * BSTRIDE + e];
        int slot = atomicAdd(&cnt[w.y], 1);
        ssrc[slot] = (int)w.x;
    }
    __syncthreads();
    for (int e = t; e < n; e += 256) s_src[base_out + e] = ssrc[e];
}

// ---------------- weight pack: fragment-ordered bf16 hi/lo ----------------
__global__ void pack_kernel(const float* __restrict__ Wl0, const float* __restrict__ Wr0,
                            const float* __restrict__ Wl1, const float* __restrict__ Wr1,
                            const float* __restrict__ Wl2, const float* __restrict__ Wr2,
                            unsigned short* __restrict__ pack) {
    int tid = blockIdx.x * blockDim.x + threadIdx.x;   // 3*32768 threads
    int l = tid >> 15;
    int r = tid & 32767;
    int k = r >> 7;
    int n = r & 127;
    const float* Wl = (l == 0) ? Wl0 : (l == 1) ? Wl1 : Wl2;
    const float* Wr = (l == 0) ? Wr0 : (l == 1) ? Wr1 : Wr2;
    float v = (k < 128) ? Wl[k * 128 + n] : Wr[(k - 128) * 128 + n];
    unsigned short hi = f2bf(v);
    unsigned short lo = f2bf(v - bf2f(hi));
    int ct = n >> 4, ks = k >> 5, lane = ((k >> 3) & 3) * 16 + (n & 15), j = k & 7;
    int idx = ((ct * 8 + ks) * 64 + lane) * 8 + j;
    pack[l * 65536 + idx] = hi;
    pack[l * 65536 + 32768 + idx] = lo;
}

// ---------------- fp32 x -> bf16 hi/lo planes ----------------
__global__ __launch_bounds__(256) void cvt_kernel(const float* __restrict__ x,
                                                  unsigned int* __restrict__ Xhi,
                                                  unsigned int* __restrict__ Xlo) {
    int i = blockIdx.x * 256 + threadIdx.x;      // N*64 uints, 2 channels each
    float2 v = ((const float2*)x)[i];
    unsigned short h0 = f2bf(v.x), h1 = f2bf(v.y);
    unsigned short l0 = f2bf(v.x - bf2f(h0)), l1 = f2bf(v.y - bf2f(h1));
    Xhi[i] = (unsigned int)h0 | ((unsigned int)h1 << 16);
    Xlo[i] = (unsigned int)l0 | ((unsigned int)l1 << 16);
}

// ---------------- mean aggregation: wave/node, 16 lanes x dwordx4 per row ----------------
// One uint4 load fetches 4 edges' worth (each 16-lane subgroup covers one 256 B row).
// 2 loads in flight per iteration = 8 rows outstanding per wave.
__global__ __launch_bounds__(256) void agg_kernel(const uint4* __restrict__ X4,
                                                  const int* __restrict__ s_src,
                                                  const int* __restrict__ offs,
                                                  float* __restrict__ mean) {
    int wid = threadIdx.x >> 6, lane = threadIdx.x & 63;
    int node = blockIdx.x * 4 + wid;
    int sub = lane >> 4, li = lane & 15;
    int beg = offs[node], end = offs[node + 1];
    float acc[8];
#pragma unroll
    for (int j = 0; j < 8; ++j) acc[j] = 0.f;

    int e = beg;
    for (; e + 8 <= end; e += 8) {
        int si0 = s_src[e + sub];
        int si1 = s_src[e + 4 + sub];
        uint4 u0 = X4[si0 * 16 + li];
        uint4 u1 = X4[si1 * 16 + li];
        const unsigned int w0[4] = {u0.x, u0.y, u0.z, u0.w};
        const unsigned int w1[4] = {u1.x, u1.y, u1.z, u1.w};
#pragma unroll
        for (int j = 0; j < 4; ++j) {
            acc[2 * j]     += bf2f((unsigned short)w0[j]) + bf2f((unsigned short)w1[j]);
            acc[2 * j + 1] += bf2f((unsigned short)(w0[j] >> 16)) + bf2f((unsigned short)(w1[j] >> 16));
        }
    }
    if (e + 4 <= end) {
        int si = s_src[e + sub];
        uint4 u = X4[si * 16 + li];
        const unsigned int w[4] = {u.x, u.y, u.z, u.w};
#pragma unroll
        for (int j = 0; j < 4; ++j) {
            acc[2 * j]     += bf2f((unsigned short)w[j]);
            acc[2 * j + 1] += bf2f((unsigned short)(w[j] >> 16));
        }
        e += 4;
    }
    int rem = end - e;
    if (rem > 0) {                       // wave-uniform branch; tail 1..3 edges
        int si = s_src[min(e + sub, end - 1)];
        uint4 u = X4[si * 16 + li];
        if (sub < rem) {
            const unsigned int w[4] = {u.x, u.y, u.z, u.w};
#pragma unroll
            for (int j = 0; j < 4; ++j) {
                acc[2 * j]     += bf2f((unsigned short)w[j]);
                acc[2 * j + 1] += bf2f((unsigned short)(w[j] >> 16));
            }
        }
    }
    // combine the 4 subgroup partials (lanes li, li+16, li+32, li+48)
#pragma unroll
    for (int j = 0; j < 8; ++j) {
        acc[j] += __shfl_xor(acc[j], 16);
        acc[j] += __shfl_xor(acc[j], 32);
    }
    float inv = 1.0f / fmaxf((float)(end - beg), 1.0f);
    if (sub < 2) {                       // 32 lanes store the 512 B row
        float4 v = make_float4(acc[sub * 4] * inv, acc[sub * 4 + 1] * inv,
                               acc[sub * 4 + 2] * inv, acc[sub * 4 + 3] * inv);
        *(float4*)&mean[node * D + li * 8 + sub * 4] = v;
    }
}

// ---------------- fused MFMA linear + LN(+ELU | +L2norm) ----------------
// out = LN(mean@Wl + bl + h@Wr); h in/out as bf16 hi/lo planes (in-place safe:
// each wave reads only its own 32 rows, writes them after).
__global__ __launch_bounds__(256) void mmln_kernel(unsigned short* Xh,  // in/out hi plane
                                                   unsigned short* Xl,  // in/out lo plane
                                                   const float* __restrict__ mean,
                                                   const unsigned short* __restrict__ packh,
                                                   const unsigned short* __restrict__ packl,
                                                   const float* __restrict__ bl,
                                                   const float* __restrict__ g,
                                                   const float* __restrict__ b,
                                                   float* __restrict__ outf, int last) {
    int t = threadIdx.x;
    int lane = t & 63;
    int wid = t >> 6;
    int colb = lane & 15;
    int quad = lane >> 4;
    int kq = quad * 8;
    int tilebase = blockIdx.x * 128 + wid * 32;

    int rowA[2];
    rowA[0] = min(tilebase + colb, N_NODES - 1);
    rowA[1] = min(tilebase + 16 + colb, N_NODES - 1);

    floatx4 acc[2][8];
#pragma unroll
    for (int rt = 0; rt < 2; ++rt)
#pragma unroll
        for (int ct = 0; ct < 8; ++ct) acc[rt][ct] = (floatx4){0.f, 0.f, 0.f, 0.f};

    // ---- ks 0..3: mean @ Wl (fp32 mean -> split hi/lo in-register) ----
#pragma unroll
    for (int ks = 0; ks < 4; ++ks) {
        int kof = ks * 32 + kq;
        short8 ah[2], al[2];
#pragma unroll
        for (int rt = 0; rt < 2; ++rt) {
            const float* p = mean + (long)rowA[rt] * D + kof;
            float4 v0 = *(const float4*)p;
            float4 v1 = *(const float4*)(p + 4);
            float v[8] = {v0.x, v0.y, v0.z, v0.w, v1.x, v1.y, v1.z, v1.w};
#pragma unroll
            for (int j = 0; j < 8; ++j) {
                unsigned short hi = f2bf(v[j]);
                ah[rt][j] = (short)hi;
                al[rt][j] = (short)f2bf(v[j] - bf2f(hi));
            }
        }
#pragma unroll
        for (int ct = 0; ct < 8; ++ct) {
            int fo = ((ct * 8 + ks) << 9) + (lane << 3);
            short8 bh = *(const short8*)(packh + fo);
            short8 bo = *(const short8*)(packl + fo);
#pragma unroll
            for (int rt = 0; rt < 2; ++rt) {
                acc[rt][ct] = __builtin_amdgcn_mfma_f32_16x16x32_bf16(ah[rt], bh, acc[rt][ct], 0, 0, 0);
                acc[rt][ct] = __builtin_amdgcn_mfma_f32_16x16x32_bf16(al[rt], bh, acc[rt][ct], 0, 0, 0);
                acc[rt][ct] = __builtin_amdgcn_mfma_f32_16x16x32_bf16(ah[rt], bo, acc[rt][ct], 0, 0, 0);
            }
        }
    }
    // ---- ks 4..7: h @ Wr (hi/lo planes loaded directly as fragments) ----
#pragma unroll
    for (int ks = 4; ks < 8; ++ks) {
        int kof = (ks - 4) * 32 + kq;
        short8 ah[2], al[2];
#pragma unroll
        for (int rt = 0; rt < 2; ++rt) {
            long o = (long)rowA[rt] * D + kof;
            ah[rt] = *(const short8*)(Xh + o);
            al[rt] = *(const short8*)(Xl + o);
        }
#pragma unroll
        for (int ct = 0; ct < 8; ++ct) {
            int fo = ((ct * 8 + ks) << 9) + (lane << 3);
            short8 bh = *(const short8*)(packh + fo);
            short8 bo = *(const short8*)(packl + fo);
#pragma unroll
            for (int rt = 0; rt < 2; ++rt) {
                acc[rt][ct] = __builtin_amdgcn_mfma_f32_16x16x32_bf16(ah[rt], bh, acc[rt][ct], 0, 0, 0);
                acc[rt][ct] = __builtin_amdgcn_mfma_f32_16x16x32_bf16(al[rt], bh, acc[rt][ct], 0, 0, 0);
                acc[rt][ct] = __builtin_amdgcn_mfma_f32_16x16x32_bf16(ah[rt], bo, acc[rt][ct], 0, 0, 0);
            }
        }
    }

    float bb[8], gg[8], b2[8];
#pragma unroll
    for (int ct = 0; ct < 8; ++ct) {
        bb[ct] = bl[ct * 16 + colb];
        gg[ct] = g[ct * 16 + colb];
        b2[ct] = b[ct * 16 + colb];
    }

#pragma unroll
    for (int rt = 0; rt < 2; ++rt) {
#pragma unroll
        for (int ct = 0; ct < 8; ++ct)
#pragma unroll
            for (int e = 0; e < 4; ++e) acc[rt][ct][e] += bb[ct];
        float mu[4], rstd[4];
#pragma unroll
        for (int e = 0; e < 4; ++e) {
            float s = 0.f;
#pragma unroll
            for (int ct = 0; ct < 8; ++ct) s += acc[rt][ct][e];
            s += __shfl_xor(s, 1); s += __shfl_xor(s, 2);
            s += __shfl_xor(s, 4); s += __shfl_xor(s, 8);
            mu[e] = s * (1.0f / 128.0f);
        }
#pragma unroll
        for (int e = 0; e < 4; ++e) {
            float q = 0.f;
#pragma unroll
            for (int ct = 0; ct < 8; ++ct) {
                float d = acc[rt][ct][e] - mu[e];
                q += d * d;
            }
            q += __shfl_xor(q, 1); q += __shfl_xor(q, 2);
            q += __shfl_xor(q, 4); q += __shfl_xor(q, 8);
            rstd[e] = rsqrtf(q * (1.0f / 128.0f) + 1e-5f);
        }
#pragma unroll
        for (int ct = 0; ct < 8; ++ct)
#pragma unroll
            for (int e = 0; e < 4; ++e) {
                float y = (acc[rt][ct][e] - mu[e]) * rstd[e] * gg[ct] + b2[ct];
                if (!last) y = (y > 0.f) ? y : expm1f(y);
                acc[rt][ct][e] = y;
            }
        if (last) {
#pragma unroll
            for (int e = 0; e < 4; ++e) {
                float ss = 0.f;
#pragma unroll
                for (int ct = 0; ct < 8; ++ct) {
                    float y = acc[rt][ct][e];
                    ss += y * y;
                }
                ss += __shfl_xor(ss, 1); ss += __shfl_xor(ss, 2);
                ss += __shfl_xor(ss, 4); ss += __shfl_xor(ss, 8);
                float inv = 1.0f / fmaxf(sqrtf(ss), 1e-12f);
#pragma unroll
                for (int ct = 0; ct < 8; ++ct) acc[rt][ct][e] *= inv;
            }
#pragma unroll
            for (int e = 0; e < 4; ++e) {
                int row = tilebase + rt * 16 + quad * 4 + e;
                if (row < N_NODES) {
#pragma unroll
                    for (int ct = 0; ct < 8; ++ct)
                        outf[(long)row * D + ct * 16 + colb] = acc[rt][ct][e];
                }
            }
        } else {
#pragma unroll
            for (int e = 0; e < 4; ++e) {
                int row = tilebase + rt * 16 + quad * 4 + e;
                if (row < N_NODES) {
#pragma unroll
                    for (int ct = 0; ct < 8; ++ct) {
                        float y = acc[rt][ct][e];
                        unsigned short hh = f2bf(y);
                        unsigned short ll = f2bf(y - bf2f(hh));
                        long o = (long)row * D + ct * 16 + colb;
                        Xh[o] = hh;
                        Xl[o] = ll;
                    }
                }
            }
        }
    }
}

extern "C" void kernel_launch(void* const* d_in, const int* in_sizes, int n_in,
                              void* d_out, int out_size, void* d_ws, size_t ws_size,
                              hipStream_t stream) {
    const float* x = (const float*)d_in[0];
    const int* edges = (const int*)d_in[1];
    const int* src = edges;
    const int* dst = edges + N_EDGES;
    const float* Wl[3] = {(const float*)d_in[2], (const float*)d_in[7],  (const float*)d_in[12]};
    const float* bl[3] = {(const float*)d_in[3], (const float*)d_in[8],  (const float*)d_in[13]};
    const float* Wr[3] = {(const float*)d_in[4], (const float*)d_in[9],  (const float*)d_in[14]};
    const float* g[3]  = {(const float*)d_in[5], (const float*)d_in[10], (const float*)d_in[15]};
    const float* b[3]  = {(const float*)d_in[6], (const float*)d_in[11], (const float*)d_in[16]};

    char* ws = (char*)d_ws;
    int* s_src = (int*)(ws + OFF_SSRC);
    int* offs  = (int*)(ws + OFF_OFFS);
    unsigned short* wpack = (unsigned short*)(ws + OFF_PACK);
    int* gcur  = (int*)(ws + OFF_GC);
    int* bbase = (int*)(ws + OFF_BB);
    float* M = (float*)(ws + OFF_M);
    uint2* staging = (uint2*)(ws + OFF_M);     // aliases M; dead before first agg
    unsigned short* Xhi = (unsigned short*)(ws + OFF_XHI);
    unsigned short* Xlo = (unsigned short*)(ws + OFF_XLO);
    float* out = (float*)d_out;

    // ---- locality-preserving bucket sort of edges by dst ----
    hipMemsetAsync(gcur, 0, NB * sizeof(int), stream);
    part_kernel<<<(N_EDGES + 4095) / 4096, 256, 0, stream>>>(src, dst, gcur, staging);
    bscan_kernel<<<1, 512, 0, stream>>>(gcur, bbase, offs);
    bsort_kernel<<<NB, 256, 0, stream>>>(staging, gcur, bbase, offs, s_src);
    // weights -> bf16 hi/lo fragments; x -> bf16 hi/lo planes
    pack_kernel<<<(3 * 32768) / 256, 256, 0, stream>>>(Wl[0], Wr[0], Wl[1], Wr[1], Wl[2], Wr[2], wpack);
    cvt_kernel<<<(N_NODES * 64) / 256, 256, 0, stream>>>(x, (unsigned int*)Xhi, (unsigned int*)Xlo);

    const int MMB = (N_NODES + 127) / 128;  // 782
    unsigned short* ph[3] = {wpack, wpack + 65536, wpack + 131072};

    // ---- layer 0 ----
    agg_kernel<<<N_NODES / 4, 256, 0, stream>>>((const uint4*)Xhi, s_src, offs, M);
    mmln_kernel<<<MMB, 256, 0, stream>>>(Xhi, Xlo, M, ph[0], ph[0] + 32768, bl[0], g[0], b[0], nullptr, 0);
    // ---- layer 1 ----
    agg_kernel<<<N_NODES / 4, 256, 0, stream>>>((const uint4*)Xhi, s_src, offs, M);
    mmln_kernel<<<MMB, 256, 0, stream>>>(Xhi, Xlo, M, ph[1], ph[1] + 32768, bl[1], g[1], b[1], nullptr, 0);
    // ---- layer 2 ----
    agg_kernel<<<N_NODES / 4, 256, 0, stream>>>((const uint4*)Xhi, s_src, offs, M);
    mmln_kernel<<<MMB, 256, 0, stream>>>(Xhi, Xlo, M, ph[2], ph[2] + 32768, bl[2], g[2], b[2], out, 1);
}